// Round 12
// baseline (3330.208 us; speedup 1.0000x reference)
//
#include <hip/hip_runtime.h>
#include <math.h>

#define B_ 8
#define N_ 1024
#define D_ 768
#define H_ 12
#define Y_ 64
#define M_ 3072
#define STEPS_ 12
#define ALPHA_ 0.1f
#define BETA_ 0.125f
#define EPS_ 1e-5f
#define LOG2E_ 1.44269504f

typedef __attribute__((ext_vector_type(8))) short bf16x8;
typedef __attribute__((ext_vector_type(8))) unsigned short u16x8;
typedef __attribute__((ext_vector_type(4))) float f32x4;

__device__ inline unsigned short f2bf(float f) {
  union { float f; unsigned int u; } v; v.f = f;
  unsigned int r = (v.u + 0x7fffu + ((v.u >> 16) & 1u)) >> 16;
  return (unsigned short)r;
}

// raw 2^x / log2(x) (v_exp_f32 / v_log_f32; VALU interlocked, no hazards)
__device__ inline float exp2_fast(float x) {
  float r;
  asm("v_exp_f32 %0, %1" : "=v"(r) : "v"(x));
  return r;
}
__device__ inline float log2_fast(float x) {
  float r;
  asm("v_log_f32 %0, %1" : "=v"(r) : "v"(x));
  return r;
}

__device__ inline void async_copy16(const void* g, void* l) {
  __builtin_amdgcn_global_load_lds(
      (const __attribute__((address_space(1))) unsigned int*)g,
      (__attribute__((address_space(3))) unsigned int*)l, 16, 0, 0);
}

// bijective XCD-aware remap of a 1D grid (m204 formula)
__device__ inline int xcd_remap(int bid, int nwg) {
  const int qd = nwg >> 3, rm = nwg & 7;
  const int xcd = bid & 7, idx = bid >> 3;
  return (xcd < rm ? xcd * (qd + 1) : rm * (qd + 1) + (xcd - rm) * qd) + idx;
}

// ---------------------------------------------------------------------------
// LayerNorm -> bf16 g. 192 threads (3 waves), float4 loads, uint2 stores.
// ---------------------------------------------------------------------------
__global__ __launch_bounds__(192) void ln_kernel(const float* __restrict__ x,
    const float* __restrict__ gamma, const float* __restrict__ beta,
    unsigned short* __restrict__ g) {
  const int row = blockIdx.x;
  const int t = threadIdx.x;                 // 0..191, covers 768 = 192*4
  const float* xr = x + (size_t)row * D_;
  const float4 v = *(const float4*)(xr + t * 4);
  float s = v.x + v.y + v.z + v.w;
  float sq = v.x * v.x + v.y * v.y + v.z * v.z + v.w * v.w;
  #pragma unroll
  for (int off = 1; off < 64; off <<= 1) {
    s += __shfl_xor(s, off);
    sq += __shfl_xor(sq, off);
  }
  __shared__ float ss[3], ssq[3];
  const int wid = t >> 6;
  if ((t & 63) == 0) { ss[wid] = s; ssq[wid] = sq; }
  __syncthreads();
  s = ss[0] + ss[1] + ss[2];
  sq = ssq[0] + ssq[1] + ssq[2];
  const float mu = s * (1.0f / D_);
  const float var = sq * (1.0f / D_) - mu * mu;
  const float r = rsqrtf(var + EPS_);
  const float4 gm = *(const float4*)(gamma + t * 4);
  const float4 bt = *(const float4*)(beta + t * 4);
  const unsigned int r0 = f2bf(gm.x * (v.x - mu) * r + bt.x);
  const unsigned int r1 = f2bf(gm.y * (v.y - mu) * r + bt.y);
  const unsigned int r2 = f2bf(gm.z * (v.z - mu) * r + bt.z);
  const unsigned int r3 = f2bf(gm.w * (v.w - mu) * r + bt.w);
  uint2 pk = {r0 | (r1 << 16), r2 | (r3 << 16)};
  *(uint2*)(g + (size_t)row * D_ + t * 4) = pk;
}

// fp32 -> bf16 convert with scale
__global__ __launch_bounds__(256) void cvt_bf16(const float* __restrict__ in,
    unsigned short* __restrict__ out, int n, float scale) {
  int i = blockIdx.x * 256 + threadIdx.x;
  if (i < n) out[i] = f2bf(in[i] * scale);
}

// transpose + convert + scale: in[R][C] f32 -> out[c][koff + r] bf16, stride ldo
__global__ __launch_bounds__(256) void transpose_cvt(const float* __restrict__ in,
    unsigned short* __restrict__ out, int R, int C, int ldo, int koff, float scale) {
  __shared__ float tile[32][33];
  const int c0 = blockIdx.x * 32, r0 = blockIdx.y * 32;
  const int tx = threadIdx.x & 31, ty = threadIdx.x >> 5;
  #pragma unroll
  for (int i = 0; i < 32; i += 8)
    tile[ty + i][tx] = in[(size_t)(r0 + ty + i) * C + c0 + tx];
  __syncthreads();
  #pragma unroll
  for (int i = 0; i < 32; i += 8)
    out[(size_t)(c0 + ty + i) * ldo + koff + r0 + tx] = f2bf(tile[tx][ty + i] * scale);
}

// ---------------------------------------------------------------------------
// bf16 MFMA GEMM 128x128, NT: C[*,N] = A[*,K] * B[N,K]^T, bf16 out (opt relu)
// WRT: additionally scatter transposed per-head copies into qT/kT [B,H,Y,N]
// ---------------------------------------------------------------------------
template <bool RELU, bool WRT>
__global__ __launch_bounds__(256) void gemm128(
    const unsigned short* __restrict__ A, const unsigned short* __restrict__ Bm,
    unsigned short* __restrict__ C, int N, int K, int gridN,
    unsigned short* __restrict__ qT, unsigned short* __restrict__ kT) {
  __shared__ __align__(16) unsigned short As[128 * 64];
  __shared__ __align__(16) unsigned short Bs[128 * 64];
  const int t = threadIdx.x;
  const int f = xcd_remap(blockIdx.x, gridDim.x);
  const int n0 = (f % gridN) * 128;
  const int m0 = (f / gridN) * 128;
  const int w = t >> 6;
  const int l = t & 63;
  const int wr = (w >> 1) * 64;
  const int wc = (w & 1) * 64;

  f32x4 acc[4][4];
  #pragma unroll
  for (int m = 0; m < 4; ++m)
    #pragma unroll
    for (int n = 0; n < 4; ++n) {
      f32x4 z = {0.f, 0.f, 0.f, 0.f};
      acc[m][n] = z;
    }

  for (int kt = 0; kt < K; kt += 64) {
    #pragma unroll
    for (int i = 0; i < 4; ++i) {
      const int flat = i * 4096 + t * 16;
      const int row = flat >> 7;
      const int slog = ((flat >> 4) & 7) ^ (row & 7);
      async_copy16(A + (size_t)(m0 + row) * K + kt + slog * 8, (char*)As + flat);
      async_copy16(Bm + (size_t)(n0 + row) * K + kt + slog * 8, (char*)Bs + flat);
    }
    __syncthreads();
    #pragma unroll
    for (int kk = 0; kk < 2; ++kk) {
      bf16x8 a[4], b[4];
      const int lr = l & 15;
      const int sl = kk * 4 + (l >> 4);
      #pragma unroll
      for (int m = 0; m < 4; ++m) {
        const int row = wr + m * 16 + lr;
        a[m] = *(const bf16x8*)((const char*)As + row * 128 + ((sl ^ (row & 7)) << 4));
      }
      #pragma unroll
      for (int n = 0; n < 4; ++n) {
        const int row = wc + n * 16 + lr;
        b[n] = *(const bf16x8*)((const char*)Bs + row * 128 + ((sl ^ (row & 7)) << 4));
      }
      #pragma unroll
      for (int m = 0; m < 4; ++m)
        #pragma unroll
        for (int n = 0; n < 4; ++n)
          acc[m][n] = __builtin_amdgcn_mfma_f32_16x16x32_bf16(a[m], b[n], acc[m][n], 0, 0, 0);
    }
    __syncthreads();
  }

  const int cr = (l >> 4) * 4;
  const int cc = l & 15;
  #pragma unroll
  for (int m = 0; m < 4; ++m)
    #pragma unroll
    for (int n = 0; n < 4; ++n) {
      const int col = n0 + wc + n * 16 + cc;
      unsigned long long pk = 0;
      #pragma unroll
      for (int j = 0; j < 4; ++j) {
        const int row = m0 + wr + m * 16 + cr + j;
        float v = acc[m][n][j];
        if (RELU) v = v > 0.f ? v : 0.f;
        const unsigned short bv = f2bf(v);
        C[(size_t)row * N + col] = bv;
        if (WRT) pk |= (unsigned long long)bv << (16 * j);
      }
      if (WRT) {
        const int row0 = m0 + wr + m * 16 + cr;         // 4-aligned token index
        const int bb = row0 >> 10, nn = row0 & 1023;
        const int hy = (col < 768) ? col : (col - 768); // 768 not pow2: no mask
        unsigned short* T = (col < 768) ? qT : kT;
        *(unsigned long long*)(T + ((size_t)bb * 768 + hy) * N_ + nn) = pk;
      }
    }
}

// ---------------------------------------------------------------------------
// Fused update GEMM (BK=64, K-loop split to drop per-iter A-source select):
// x[m][n] += alpha * sum_k Acat[m][k] * B2[n][k]
// Acat = [AqAk (ld 1536) | hid (ld 3072)] split at k=1536; K=4608, N=768.
// ---------------------------------------------------------------------------
__global__ __launch_bounds__(256) void gemm_update(
    const unsigned short* __restrict__ A1,  // AqAk, ld 1536
    const unsigned short* __restrict__ A2,  // hid, ld 3072
    const unsigned short* __restrict__ B2,  // [768][4608]
    float* __restrict__ x,                  // ld 768
    float alpha) {
  __shared__ __align__(16) unsigned short As[128 * 64];
  __shared__ __align__(16) unsigned short Bs[64 * 64];
  const int t = threadIdx.x;
  const int f = xcd_remap(blockIdx.x, gridDim.x);
  const int n0 = (f % 12) * 64;
  const int m0 = (f / 12) * 128;
  const int w = t >> 6;
  const int l = t & 63;
  const int wr = (w >> 1) * 64;
  const int wc = (w & 1) * 32;

  f32x4 acc[4][2];
  #pragma unroll
  for (int m = 0; m < 4; ++m)
    #pragma unroll
    for (int n = 0; n < 2; ++n) {
      f32x4 z = {0.f, 0.f, 0.f, 0.f};
      acc[m][n] = z;
    }

  auto kstep = [&](const unsigned short* __restrict__ Asrc, int lda, int kt,
                   int ktb) {
    #pragma unroll
    for (int i = 0; i < 4; ++i) {
      const int flat = i * 4096 + t * 16;
      const int row = flat >> 7;
      const int slog = ((flat >> 4) & 7) ^ (row & 7);
      async_copy16(Asrc + (size_t)(m0 + row) * lda + kt + slog * 8, (char*)As + flat);
    }
    #pragma unroll
    for (int i = 0; i < 2; ++i) {
      const int flat = i * 4096 + t * 16;
      const int row = flat >> 7;
      const int slog = ((flat >> 4) & 7) ^ (row & 7);
      async_copy16(B2 + (size_t)(n0 + row) * 4608 + ktb + slog * 8, (char*)Bs + flat);
    }
    __syncthreads();
    #pragma unroll
    for (int kk = 0; kk < 2; ++kk) {
      bf16x8 a[4], b[2];
      const int lr = l & 15;
      const int sl = kk * 4 + (l >> 4);
      #pragma unroll
      for (int m = 0; m < 4; ++m) {
        const int row = wr + m * 16 + lr;
        a[m] = *(const bf16x8*)((const char*)As + row * 128 + ((sl ^ (row & 7)) << 4));
      }
      #pragma unroll
      for (int n = 0; n < 2; ++n) {
        const int row = wc + n * 16 + lr;
        b[n] = *(const bf16x8*)((const char*)Bs + row * 128 + ((sl ^ (row & 7)) << 4));
      }
      #pragma unroll
      for (int m = 0; m < 4; ++m)
        #pragma unroll
        for (int n = 0; n < 2; ++n)
          acc[m][n] = __builtin_amdgcn_mfma_f32_16x16x32_bf16(a[m], b[n], acc[m][n], 0, 0, 0);
    }
    __syncthreads();
  };

  for (int kt = 0; kt < 1536; kt += 64) kstep(A1, 1536, kt, kt);
  for (int kt = 0; kt < 3072; kt += 64) kstep(A2, 3072, kt, kt + 1536);

  const int cr = (l >> 4) * 4;
  const int cc = l & 15;
  #pragma unroll
  for (int m = 0; m < 4; ++m)
    #pragma unroll
    for (int n = 0; n < 2; ++n) {
      const int col = n0 + wc + n * 16 + cc;
      #pragma unroll
      for (int j = 0; j < 4; ++j) {
        const int row = m0 + wr + m * 16 + cr + j;
        float* cp = x + (size_t)row * 768 + col;
        *cp += alpha * acc[m][n][j];
      }
    }
}

// ---------------------------------------------------------------------------
// Attention pass 1 (MFMA flash), QBLK=128 (8 waves), KVBLK=128.
// q pre-scaled by beta*log2e -> S is log2-domain; p = 2^(s-m) (v_exp_f32).
// Defer-max: skip rescale when tile max within +11.54 (= 8 nats).
// ---------------------------------------------------------------------------
__global__ __launch_bounds__(512) void attn1_mfma(
    const unsigned short* __restrict__ qk, const unsigned short* __restrict__ kT,
    unsigned short* __restrict__ AqAk, float* __restrict__ lse) {
  __shared__ __align__(16) unsigned short Ks[128 * 64];
  __shared__ __align__(16) unsigned short KTs[64 * 128];
  __shared__ __align__(16) unsigned short Ps[8 * 16 * 128];
  const int n0 = blockIdx.x * 128;
  const int h = blockIdx.y;
  const int b = blockIdx.z;
  const int t = threadIdx.x;
  const int w = t >> 6;            // 0..7
  const int l = t & 63;
  const int g = l >> 4;
  const int ql = l & 15;
  char* psw = (char*)(Ps + w * 2048);
  const int LD = 1536;

  bf16x8 qf[2];
  {
    const unsigned short* qrow =
        qk + ((size_t)(b * N_ + n0 + w * 16 + ql)) * LD + h * Y_;
    qf[0] = *(const bf16x8*)(qrow + g * 8);
    qf[1] = *(const bf16x8*)(qrow + 32 + g * 8);
  }
  const unsigned short* kbase = qk + (size_t)b * N_ * LD + 768 + h * Y_;
  const unsigned short* kTbase = kT + ((size_t)(b * H_ + h)) * Y_ * N_;

  f32x4 acc[4];
  #pragma unroll
  for (int yf = 0; yf < 4; ++yf) { f32x4 z = {0.f,0.f,0.f,0.f}; acc[yf] = z; }
  float mmax = -1e30f, lsum = 0.f;

  for (int mc = 0; mc < N_; mc += 128) {
    // stage K tile [128 keys][64 y] and K^T tile [64 y][128 keys] (512 thr)
    #pragma unroll
    for (int i = 0; i < 2; ++i) {
      const int flat = i * 8192 + t * 16;
      const int row = flat >> 7;
      const int slog = ((flat >> 4) & 7) ^ (row & 7);
      async_copy16(kbase + (size_t)(mc + row) * LD + slog * 8, (char*)Ks + flat);
    }
    #pragma unroll
    for (int i = 0; i < 2; ++i) {
      const int flat = i * 8192 + t * 16;
      const int row = flat >> 8;
      const int slog = ((flat >> 4) & 15) ^ (row & 7);
      async_copy16(kTbase + (size_t)row * N_ + mc + slog * 8, (char*)KTs + flat);
    }
    __syncthreads();

    f32x4 s[8];
    __builtin_amdgcn_s_setprio(1);
    #pragma unroll
    for (int f = 0; f < 8; ++f) {
      f32x4 z = {0.f,0.f,0.f,0.f}; s[f] = z;
      #pragma unroll
      for (int ks = 0; ks < 2; ++ks) {
        const int key = f * 16 + ql;
        bf16x8 a = *(const bf16x8*)((const char*)Ks + key * 128 +
                                    (((ks * 4 + g) ^ (key & 7)) << 4));
        s[f] = __builtin_amdgcn_mfma_f32_16x16x32_bf16(a, qf[ks], s[f], 0, 0, 0);
      }
    }
    __builtin_amdgcn_s_setprio(0);
    // s = log2-domain scores. Tile max:
    float rm = -1e30f;
    #pragma unroll
    for (int f = 0; f < 8; ++f)
      #pragma unroll
      for (int j = 0; j < 4; ++j) rm = fmaxf(rm, s[f][j]);
    rm = fmaxf(rm, __shfl_xor(rm, 16));
    rm = fmaxf(rm, __shfl_xor(rm, 32));
    // defer-max: rescale only when needed (wave-uniform decision)
    if (!__all(rm <= mmax + 11.5416f)) {
      const float nm = fmaxf(mmax, rm);
      const float sc = exp2_fast(mmax - nm);
      lsum *= sc;
      #pragma unroll
      for (int yf = 0; yf < 4; ++yf) acc[yf] *= sc;
      mmax = nm;
    }
    float rs = 0.f;
    #pragma unroll
    for (int f = 0; f < 8; ++f) {
      unsigned short p4[4];
      #pragma unroll
      for (int j = 0; j < 4; ++j) {
        const float pvj = exp2_fast(s[f][j] - mmax);
        rs += pvj;
        p4[j] = f2bf(pvj);
      }
      unsigned long long pk = (unsigned long long)p4[0] |
          ((unsigned long long)p4[1] << 16) |
          ((unsigned long long)p4[2] << 32) |
          ((unsigned long long)p4[3] << 48);
      const int sl = (f * 4 + g) ^ ((ql & 7) << 1);
      *(unsigned long long*)(psw + ql * 256 + sl * 8) = pk;
    }
    rs += __shfl_xor(rs, 16);
    rs += __shfl_xor(rs, 32);
    lsum += rs;
    __builtin_amdgcn_s_setprio(1);
    #pragma unroll
    for (int ks2 = 0; ks2 < 4; ++ks2) {
      const int sl2 = (ks2 * 8 + g * 2) ^ ((ql & 7) << 1);
      bf16x8 pa = *(const bf16x8*)(psw + ql * 256 + sl2 * 8);
      #pragma unroll
      for (int yf = 0; yf < 4; ++yf) {
        const int y = yf * 16 + ql;
        bf16x8 bk = *(const bf16x8*)((const char*)KTs + y * 256 +
                                     (((ks2 * 4 + g) ^ (y & 7)) << 4));
        acc[yf] = __builtin_amdgcn_mfma_f32_16x16x32_bf16(pa, bk, acc[yf], 0, 0, 0);
      }
    }
    __builtin_amdgcn_s_setprio(0);
    __syncthreads();
  }

  float linv[4];
  #pragma unroll
  for (int j = 0; j < 4; ++j)
    linv[j] = 1.0f / __shfl(lsum, (g << 4) + g * 4 + j);
  #pragma unroll
  for (int yf = 0; yf < 4; ++yf)
    #pragma unroll
    for (int j = 0; j < 4; ++j) {
      const int row = n0 + w * 16 + g * 4 + j;
      AqAk[((size_t)(b * N_ + row)) * LD + h * Y_ + yf * 16 + ql] =
          f2bf(acc[yf][j] * linv[j]);
    }
  if (g == 0)
    lse[((size_t)b * H_ + h) * N_ + n0 + w * 16 + ql] = mmax + log2_fast(lsum);
}

// ---------------------------------------------------------------------------
// Attention pass 2 (MFMA), KBLK=128 (8 waves), NBLK=128.
// S log2-domain; W = 2^(s - lse). Ak carries beta*log2e scale (qT scaled),
// compensated by 1/(beta*log2e) on B2's wkT panel.
// ---------------------------------------------------------------------------
__global__ __launch_bounds__(512) void attn2_mfma(
    const unsigned short* __restrict__ qk, const unsigned short* __restrict__ qT,
    const float* __restrict__ lse, unsigned short* __restrict__ AqAk) {
  __shared__ __align__(16) unsigned short Qs[128 * 64];
  __shared__ __align__(16) unsigned short QTs[64 * 128];
  __shared__ __align__(16) unsigned short Ws[8 * 16 * 128];
  __shared__ float lse_s[128];
  const int m0 = blockIdx.x * 128;
  const int h = blockIdx.y;
  const int b = blockIdx.z;
  const int t = threadIdx.x;
  const int w = t >> 6;            // 0..7
  const int l = t & 63;
  const int g = l >> 4;
  const int ql = l & 15;
  char* wsw = (char*)(Ws + w * 2048);
  const int LD = 1536;

  bf16x8 ka[2];
  {
    const unsigned short* krow =
        qk + ((size_t)(b * N_ + m0 + w * 16 + ql)) * LD + 768 + h * Y_;
    ka[0] = *(const bf16x8*)(krow + g * 8);
    ka[1] = *(const bf16x8*)(krow + 32 + g * 8);
  }
  const unsigned short* qbase = qk + (size_t)b * N_ * LD + h * Y_;
  const unsigned short* qTbase = qT + ((size_t)(b * H_ + h)) * Y_ * N_;
  const float* lbase = lse + ((size_t)b * H_ + h) * N_;

  f32x4 acc[4];
  #pragma unroll
  for (int yf = 0; yf < 4; ++yf) { f32x4 z = {0.f,0.f,0.f,0.f}; acc[yf] = z; }

  for (int nc = 0; nc < N_; nc += 128) {
    #pragma unroll
    for (int i = 0; i < 2; ++i) {
      const int flat = i * 8192 + t * 16;
      const int row = flat >> 7;
      const int slog = ((flat >> 4) & 7) ^ (row & 7);
      async_copy16(qbase + (size_t)(nc + row) * LD + slog * 8, (char*)Qs + flat);
    }
    #pragma unroll
    for (int i = 0; i < 2; ++i) {
      const int flat = i * 8192 + t * 16;
      const int row = flat >> 8;
      const int slog = ((flat >> 4) & 15) ^ (row & 7);
      async_copy16(qTbase + (size_t)row * N_ + nc + slog * 8, (char*)QTs + flat);
    }
    if (t < 128) lse_s[t] = lbase[nc + t];
    __syncthreads();

    f32x4 s[8];
    __builtin_amdgcn_s_setprio(1);
    #pragma unroll
    for (int f = 0; f < 8; ++f) {
      f32x4 z = {0.f,0.f,0.f,0.f}; s[f] = z;
      #pragma unroll
      for (int ks = 0; ks < 2; ++ks) {
        const int qr = f * 16 + ql;
        bf16x8 a = *(const bf16x8*)((const char*)Qs + qr * 128 +
                                    (((ks * 4 + g) ^ (qr & 7)) << 4));
        s[f] = __builtin_amdgcn_mfma_f32_16x16x32_bf16(a, ka[ks], s[f], 0, 0, 0);
      }
    }
    __builtin_amdgcn_s_setprio(0);
    #pragma unroll
    for (int f = 0; f < 8; ++f) {
      unsigned short w4[4];
      #pragma unroll
      for (int j = 0; j < 4; ++j) {
        const float wv = exp2_fast(s[f][j] - lse_s[f * 16 + g * 4 + j]);
        w4[j] = f2bf(wv);
      }
      unsigned long long pk =
          (unsigned long long)w4[0] | ((unsigned long long)w4[1] << 16) |
          ((unsigned long long)w4[2] << 32) | ((unsigned long long)w4[3] << 48);
      const int sl = (f * 4 + g) ^ ((ql & 7) << 1);
      *(unsigned long long*)(wsw + ql * 256 + sl * 8) = pk;
    }
    __builtin_amdgcn_s_setprio(1);
    #pragma unroll
    for (int ks2 = 0; ks2 < 4; ++ks2) {
      const int sl2 = (ks2 * 8 + g * 2) ^ ((ql & 7) << 1);
      bf16x8 wa = *(const bf16x8*)(wsw + ql * 256 + sl2 * 8);
      #pragma unroll
      for (int yf = 0; yf < 4; ++yf) {
        const int y = yf * 16 + ql;
        bf16x8 bq = *(const bf16x8*)((const char*)QTs + y * 256 +
                                     (((ks2 * 4 + g) ^ (y & 7)) << 4));
        acc[yf] = __builtin_amdgcn_mfma_f32_16x16x32_bf16(wa, bq, acc[yf], 0, 0, 0);
      }
    }
    __builtin_amdgcn_s_setprio(0);
    __syncthreads();
  }

  #pragma unroll
  for (int yf = 0; yf < 4; ++yf)
    #pragma unroll
    for (int j = 0; j < 4; ++j) {
      const int row = m0 + w * 16 + g * 4 + j;
      AqAk[((size_t)(b * N_ + row)) * LD + 768 + h * Y_ + yf * 16 + ql] =
          f2bf(acc[yf][j]);
    }
}

// ---------------------------------------------------------------------------
extern "C" void kernel_launch(void* const* d_in, const int* in_sizes, int n_in,
                              void* d_out, int out_size, void* d_ws, size_t ws_size,
                              hipStream_t stream) {
  const float* x0    = (const float*)d_in[0];
  const float* gamma = (const float*)d_in[1];
  const float* beta  = (const float*)d_in[2];
  const float* wq    = (const float*)d_in[3];
  const float* wk    = (const float*)d_in[4];
  const float* xi    = (const float*)d_in[5];
  float* x = (float*)d_out;

  const size_t SZ = (size_t)B_ * N_ * D_;   // 6291456
  char* wsp = (char*)d_ws;
  size_t off = 0;
  auto alloc = [&](size_t bytes) -> void* {
    off = (off + 255) & ~(size_t)255;
    void* p = wsp + off;
    off += bytes;
    return p;
  };
  unsigned short* g_bf   = (unsigned short*)alloc(SZ * 2);
  unsigned short* qk_bf  = (unsigned short*)alloc(SZ * 2 * 2);        // [8192][1536]
  unsigned short* AqAk   = (unsigned short*)alloc(SZ * 2 * 2);        // [8192][1536]
  unsigned short* qT_bf  = (unsigned short*)alloc(SZ * 2);
  unsigned short* kT_bf  = (unsigned short*)alloc(SZ * 2);
  float*          lse    = (float*)alloc((size_t)B_ * H_ * N_ * 4);
  unsigned short* wqk_bf = (unsigned short*)alloc((size_t)2 * D_ * D_ * 2);   // [1536][768]
  unsigned short* xi_bf  = (unsigned short*)alloc((size_t)M_ * D_ * 2);       // [3072][768]
  unsigned short* B2_bf  = (unsigned short*)alloc((size_t)D_ * (2 * D_ + M_) * 2); // [768][4608]
  unsigned short* hid_bf = (unsigned short*)alloc((size_t)B_ * N_ * M_ * 2);  // [8192][3072]

  const int WQN = D_ * D_;
  const int XIN = M_ * D_;
  const float SQ = BETA_ * LOG2E_;           // folded into q
  // B1 for proj: [SQ*wq; wk] rows
  cvt_bf16<<<(WQN + 255) / 256, 256, 0, stream>>>(wq, wqk_bf, WQN, SQ);
  cvt_bf16<<<(WQN + 255) / 256, 256, 0, stream>>>(wk, wqk_bf + (size_t)D_ * D_, WQN, 1.0f);
  cvt_bf16<<<(XIN + 255) / 256, 256, 0, stream>>>(xi, xi_bf, XIN, 1.0f);
  // B2 = [wqT | wkT/SQ | xiT] along k, ld 4608 (1/SQ compensates Ak scale)
  const int LDB2 = 2 * D_ + M_;  // 4608
  transpose_cvt<<<dim3(D_ / 32, D_ / 32), 256, 0, stream>>>(wq, B2_bf, D_, D_, LDB2, 0, 1.0f);
  transpose_cvt<<<dim3(D_ / 32, D_ / 32), 256, 0, stream>>>(wk, B2_bf, D_, D_, LDB2, D_, 1.0f / SQ);
  transpose_cvt<<<dim3(D_ / 32, M_ / 32), 256, 0, stream>>>(xi, B2_bf, M_, D_, LDB2, 2 * D_, 1.0f);

  hipMemcpyAsync(x, x0, SZ * sizeof(float), hipMemcpyDeviceToDevice, stream);

  const int MN = B_ * N_;  // 8192
  for (int step = 0; step < STEPS_; ++step) {
    ln_kernel<<<MN, 192, 0, stream>>>(x, gamma, beta, g_bf);
    // qk = g @ [SQ*Wq;Wk]^T -> [8192][1536] bf16, with fused qT/kT scatter
    gemm128<false, true><<<(1536 / 128) * (MN / 128), 256, 0, stream>>>(
        g_bf, wqk_bf, qk_bf, 1536, D_, 1536 / 128, qT_bf, kT_bf);
    // hid = relu(g @ xi^T) -> [8192][3072] bf16
    gemm128<true, false><<<(M_ / 128) * (MN / 128), 256, 0, stream>>>(
        g_bf, xi_bf, hid_bf, M_, D_, M_ / 128, nullptr, nullptr);
    // attention gradient pieces -> AqAk  (8-wave blocks, QBLK=128)
    attn1_mfma<<<dim3(N_ / 128, H_, B_), 512, 0, stream>>>(qk_bf, kT_bf, AqAk, lse);
    attn2_mfma<<<dim3(N_ / 128, H_, B_), 512, 0, stream>>>(qk_bf, qT_bf, lse, AqAk);
    // x += alpha * [AqAk | hid] @ B2^T   (BK=64, split K-loop)
    gemm_update<<<12 * (MN / 128), 256, 0, stream>>>(
        AqAk, hid_bf, B2_bf, x, ALPHA_);
  }
}

// Round 13
// 3118.018 us; speedup vs baseline: 1.0681x; 1.0681x over previous
//
#include <hip/hip_runtime.h>
#include <math.h>

#define B_ 8
#define N_ 1024
#define D_ 768
#define H_ 12
#define Y_ 64
#define M_ 3072
#define STEPS_ 12
#define ALPHA_ 0.1f
#define BETA_ 0.125f
#define EPS_ 1e-5f
#define LOG2E_ 1.44269504f

typedef __attribute__((ext_vector_type(8))) short bf16x8;
typedef __attribute__((ext_vector_type(8))) unsigned short u16x8;
typedef __attribute__((ext_vector_type(4))) float f32x4;

__device__ inline unsigned short f2bf(float f) {
  union { float f; unsigned int u; } v; v.f = f;
  unsigned int r = (v.u + 0x7fffu + ((v.u >> 16) & 1u)) >> 16;
  return (unsigned short)r;
}

// native 2^x / log2(x) via compiler intrinsics (v_exp_f32 / v_log_f32) —
// scheduler-visible, unlike inline asm (R12 regression: asm blocked pipelining)
__device__ inline float exp2_fast(float x) { return __builtin_amdgcn_exp2f(x); }
__device__ inline float log2_fast(float x) { return __builtin_amdgcn_logf(x); }

__device__ inline void async_copy16(const void* g, void* l) {
  __builtin_amdgcn_global_load_lds(
      (const __attribute__((address_space(1))) unsigned int*)g,
      (__attribute__((address_space(3))) unsigned int*)l, 16, 0, 0);
}

// bijective XCD-aware remap of a 1D grid (m204 formula)
__device__ inline int xcd_remap(int bid, int nwg) {
  const int qd = nwg >> 3, rm = nwg & 7;
  const int xcd = bid & 7, idx = bid >> 3;
  return (xcd < rm ? xcd * (qd + 1) : rm * (qd + 1) + (xcd - rm) * qd) + idx;
}

// ---------------------------------------------------------------------------
// LayerNorm -> bf16 g. 192 threads (3 waves), float4 loads, uint2 stores.
// ---------------------------------------------------------------------------
__global__ __launch_bounds__(192) void ln_kernel(const float* __restrict__ x,
    const float* __restrict__ gamma, const float* __restrict__ beta,
    unsigned short* __restrict__ g) {
  const int row = blockIdx.x;
  const int t = threadIdx.x;                 // 0..191, covers 768 = 192*4
  const float* xr = x + (size_t)row * D_;
  const float4 v = *(const float4*)(xr + t * 4);
  float s = v.x + v.y + v.z + v.w;
  float sq = v.x * v.x + v.y * v.y + v.z * v.z + v.w * v.w;
  #pragma unroll
  for (int off = 1; off < 64; off <<= 1) {
    s += __shfl_xor(s, off);
    sq += __shfl_xor(sq, off);
  }
  __shared__ float ss[3], ssq[3];
  const int wid = t >> 6;
  if ((t & 63) == 0) { ss[wid] = s; ssq[wid] = sq; }
  __syncthreads();
  s = ss[0] + ss[1] + ss[2];
  sq = ssq[0] + ssq[1] + ssq[2];
  const float mu = s * (1.0f / D_);
  const float var = sq * (1.0f / D_) - mu * mu;
  const float r = rsqrtf(var + EPS_);
  const float4 gm = *(const float4*)(gamma + t * 4);
  const float4 bt = *(const float4*)(beta + t * 4);
  const unsigned int r0 = f2bf(gm.x * (v.x - mu) * r + bt.x);
  const unsigned int r1 = f2bf(gm.y * (v.y - mu) * r + bt.y);
  const unsigned int r2 = f2bf(gm.z * (v.z - mu) * r + bt.z);
  const unsigned int r3 = f2bf(gm.w * (v.w - mu) * r + bt.w);
  uint2 pk = {r0 | (r1 << 16), r2 | (r3 << 16)};
  *(uint2*)(g + (size_t)row * D_ + t * 4) = pk;
}

// fp32 -> bf16 convert with scale
__global__ __launch_bounds__(256) void cvt_bf16(const float* __restrict__ in,
    unsigned short* __restrict__ out, int n, float scale) {
  int i = blockIdx.x * 256 + threadIdx.x;
  if (i < n) out[i] = f2bf(in[i] * scale);
}

// transpose + convert + scale: in[R][C] f32 -> out[c][koff + r] bf16, stride ldo
__global__ __launch_bounds__(256) void transpose_cvt(const float* __restrict__ in,
    unsigned short* __restrict__ out, int R, int C, int ldo, int koff, float scale) {
  __shared__ float tile[32][33];
  const int c0 = blockIdx.x * 32, r0 = blockIdx.y * 32;
  const int tx = threadIdx.x & 31, ty = threadIdx.x >> 5;
  #pragma unroll
  for (int i = 0; i < 32; i += 8)
    tile[ty + i][tx] = in[(size_t)(r0 + ty + i) * C + c0 + tx];
  __syncthreads();
  #pragma unroll
  for (int i = 0; i < 32; i += 8)
    out[(size_t)(c0 + ty + i) * ldo + koff + r0 + tx] = f2bf(tile[tx][ty + i] * scale);
}

// ---------------------------------------------------------------------------
// bf16 MFMA GEMM 128x128, NT: C[*,N] = A[*,K] * B[N,K]^T, bf16 out (opt relu)
// WRT: additionally scatter transposed per-head copies into qT/kT [B,H,Y,N]
// ---------------------------------------------------------------------------
template <bool RELU, bool WRT>
__global__ __launch_bounds__(256) void gemm128(
    const unsigned short* __restrict__ A, const unsigned short* __restrict__ Bm,
    unsigned short* __restrict__ C, int N, int K, int gridN,
    unsigned short* __restrict__ qT, unsigned short* __restrict__ kT) {
  __shared__ __align__(16) unsigned short As[128 * 64];
  __shared__ __align__(16) unsigned short Bs[128 * 64];
  const int t = threadIdx.x;
  const int f = xcd_remap(blockIdx.x, gridDim.x);
  const int n0 = (f % gridN) * 128;
  const int m0 = (f / gridN) * 128;
  const int w = t >> 6;
  const int l = t & 63;
  const int wr = (w >> 1) * 64;
  const int wc = (w & 1) * 64;

  f32x4 acc[4][4];
  #pragma unroll
  for (int m = 0; m < 4; ++m)
    #pragma unroll
    for (int n = 0; n < 4; ++n) {
      f32x4 z = {0.f, 0.f, 0.f, 0.f};
      acc[m][n] = z;
    }

  for (int kt = 0; kt < K; kt += 64) {
    #pragma unroll
    for (int i = 0; i < 4; ++i) {
      const int flat = i * 4096 + t * 16;
      const int row = flat >> 7;
      const int slog = ((flat >> 4) & 7) ^ (row & 7);
      async_copy16(A + (size_t)(m0 + row) * K + kt + slog * 8, (char*)As + flat);
      async_copy16(Bm + (size_t)(n0 + row) * K + kt + slog * 8, (char*)Bs + flat);
    }
    __syncthreads();
    #pragma unroll
    for (int kk = 0; kk < 2; ++kk) {
      bf16x8 a[4], b[4];
      const int lr = l & 15;
      const int sl = kk * 4 + (l >> 4);
      #pragma unroll
      for (int m = 0; m < 4; ++m) {
        const int row = wr + m * 16 + lr;
        a[m] = *(const bf16x8*)((const char*)As + row * 128 + ((sl ^ (row & 7)) << 4));
      }
      #pragma unroll
      for (int n = 0; n < 4; ++n) {
        const int row = wc + n * 16 + lr;
        b[n] = *(const bf16x8*)((const char*)Bs + row * 128 + ((sl ^ (row & 7)) << 4));
      }
      #pragma unroll
      for (int m = 0; m < 4; ++m)
        #pragma unroll
        for (int n = 0; n < 4; ++n)
          acc[m][n] = __builtin_amdgcn_mfma_f32_16x16x32_bf16(a[m], b[n], acc[m][n], 0, 0, 0);
    }
    __syncthreads();
  }

  const int cr = (l >> 4) * 4;
  const int cc = l & 15;
  #pragma unroll
  for (int m = 0; m < 4; ++m)
    #pragma unroll
    for (int n = 0; n < 4; ++n) {
      const int col = n0 + wc + n * 16 + cc;
      unsigned long long pk = 0;
      #pragma unroll
      for (int j = 0; j < 4; ++j) {
        const int row = m0 + wr + m * 16 + cr + j;
        float v = acc[m][n][j];
        if (RELU) v = v > 0.f ? v : 0.f;
        const unsigned short bv = f2bf(v);
        C[(size_t)row * N + col] = bv;
        if (WRT) pk |= (unsigned long long)bv << (16 * j);
      }
      if (WRT) {
        const int row0 = m0 + wr + m * 16 + cr;         // 4-aligned token index
        const int bb = row0 >> 10, nn = row0 & 1023;
        const int hy = (col < 768) ? col : (col - 768); // 768 not pow2: no mask
        unsigned short* T = (col < 768) ? qT : kT;
        *(unsigned long long*)(T + ((size_t)bb * 768 + hy) * N_ + nn) = pk;
      }
    }
}

// ---------------------------------------------------------------------------
// Fused update GEMM (BK=64, K-loop split to drop per-iter A-source select):
// x[m][n] += alpha * sum_k Acat[m][k] * B2[n][k]
// Acat = [AqAk (ld 1536) | hid (ld 3072)] split at k=1536; K=4608, N=768.
// ---------------------------------------------------------------------------
__global__ __launch_bounds__(256) void gemm_update(
    const unsigned short* __restrict__ A1,  // AqAk, ld 1536
    const unsigned short* __restrict__ A2,  // hid, ld 3072
    const unsigned short* __restrict__ B2,  // [768][4608]
    float* __restrict__ x,                  // ld 768
    float alpha) {
  __shared__ __align__(16) unsigned short As[128 * 64];
  __shared__ __align__(16) unsigned short Bs[64 * 64];
  const int t = threadIdx.x;
  const int f = xcd_remap(blockIdx.x, gridDim.x);
  const int n0 = (f % 12) * 64;
  const int m0 = (f / 12) * 128;
  const int w = t >> 6;
  const int l = t & 63;
  const int wr = (w >> 1) * 64;
  const int wc = (w & 1) * 32;

  f32x4 acc[4][2];
  #pragma unroll
  for (int m = 0; m < 4; ++m)
    #pragma unroll
    for (int n = 0; n < 2; ++n) {
      f32x4 z = {0.f, 0.f, 0.f, 0.f};
      acc[m][n] = z;
    }

  auto kstep = [&](const unsigned short* __restrict__ Asrc, int lda, int kt,
                   int ktb) {
    #pragma unroll
    for (int i = 0; i < 4; ++i) {
      const int flat = i * 4096 + t * 16;
      const int row = flat >> 7;
      const int slog = ((flat >> 4) & 7) ^ (row & 7);
      async_copy16(Asrc + (size_t)(m0 + row) * lda + kt + slog * 8, (char*)As + flat);
    }
    #pragma unroll
    for (int i = 0; i < 2; ++i) {
      const int flat = i * 4096 + t * 16;
      const int row = flat >> 7;
      const int slog = ((flat >> 4) & 7) ^ (row & 7);
      async_copy16(B2 + (size_t)(n0 + row) * 4608 + ktb + slog * 8, (char*)Bs + flat);
    }
    __syncthreads();
    #pragma unroll
    for (int kk = 0; kk < 2; ++kk) {
      bf16x8 a[4], b[2];
      const int lr = l & 15;
      const int sl = kk * 4 + (l >> 4);
      #pragma unroll
      for (int m = 0; m < 4; ++m) {
        const int row = wr + m * 16 + lr;
        a[m] = *(const bf16x8*)((const char*)As + row * 128 + ((sl ^ (row & 7)) << 4));
      }
      #pragma unroll
      for (int n = 0; n < 2; ++n) {
        const int row = wc + n * 16 + lr;
        b[n] = *(const bf16x8*)((const char*)Bs + row * 128 + ((sl ^ (row & 7)) << 4));
      }
      #pragma unroll
      for (int m = 0; m < 4; ++m)
        #pragma unroll
        for (int n = 0; n < 2; ++n)
          acc[m][n] = __builtin_amdgcn_mfma_f32_16x16x32_bf16(a[m], b[n], acc[m][n], 0, 0, 0);
    }
    __syncthreads();
  };

  for (int kt = 0; kt < 1536; kt += 64) kstep(A1, 1536, kt, kt);
  for (int kt = 0; kt < 3072; kt += 64) kstep(A2, 3072, kt, kt + 1536);

  const int cr = (l >> 4) * 4;
  const int cc = l & 15;
  #pragma unroll
  for (int m = 0; m < 4; ++m)
    #pragma unroll
    for (int n = 0; n < 2; ++n) {
      const int col = n0 + wc + n * 16 + cc;
      #pragma unroll
      for (int j = 0; j < 4; ++j) {
        const int row = m0 + wr + m * 16 + cr + j;
        float* cp = x + (size_t)row * 768 + col;
        *cp += alpha * acc[m][n][j];
      }
    }
}

// ---------------------------------------------------------------------------
// Attention pass 1 (MFMA flash), QBLK=128 (8 waves), KVBLK=128.
// q pre-scaled by beta*log2e -> S is log2-domain; p = 2^(s-m) (native exp2).
// Defer-max: skip rescale when tile max within +11.54 (= 8 nats).
// ---------------------------------------------------------------------------
__global__ __launch_bounds__(512) void attn1_mfma(
    const unsigned short* __restrict__ qk, const unsigned short* __restrict__ kT,
    unsigned short* __restrict__ AqAk, float* __restrict__ lse) {
  __shared__ __align__(16) unsigned short Ks[128 * 64];
  __shared__ __align__(16) unsigned short KTs[64 * 128];
  __shared__ __align__(16) unsigned short Ps[8 * 16 * 128];
  const int n0 = blockIdx.x * 128;
  const int h = blockIdx.y;
  const int b = blockIdx.z;
  const int t = threadIdx.x;
  const int w = t >> 6;            // 0..7
  const int l = t & 63;
  const int g = l >> 4;
  const int ql = l & 15;
  char* psw = (char*)(Ps + w * 2048);
  const int LD = 1536;

  bf16x8 qf[2];
  {
    const unsigned short* qrow =
        qk + ((size_t)(b * N_ + n0 + w * 16 + ql)) * LD + h * Y_;
    qf[0] = *(const bf16x8*)(qrow + g * 8);
    qf[1] = *(const bf16x8*)(qrow + 32 + g * 8);
  }
  const unsigned short* kbase = qk + (size_t)b * N_ * LD + 768 + h * Y_;
  const unsigned short* kTbase = kT + ((size_t)(b * H_ + h)) * Y_ * N_;

  f32x4 acc[4];
  #pragma unroll
  for (int yf = 0; yf < 4; ++yf) { f32x4 z = {0.f,0.f,0.f,0.f}; acc[yf] = z; }
  float mmax = -1e30f, lsum = 0.f;

  for (int mc = 0; mc < N_; mc += 128) {
    // stage K tile [128 keys][64 y] and K^T tile [64 y][128 keys] (512 thr)
    #pragma unroll
    for (int i = 0; i < 2; ++i) {
      const int flat = i * 8192 + t * 16;
      const int row = flat >> 7;
      const int slog = ((flat >> 4) & 7) ^ (row & 7);
      async_copy16(kbase + (size_t)(mc + row) * LD + slog * 8, (char*)Ks + flat);
    }
    #pragma unroll
    for (int i = 0; i < 2; ++i) {
      const int flat = i * 8192 + t * 16;
      const int row = flat >> 8;
      const int slog = ((flat >> 4) & 15) ^ (row & 7);
      async_copy16(kTbase + (size_t)row * N_ + mc + slog * 8, (char*)KTs + flat);
    }
    __syncthreads();

    f32x4 s[8];
    __builtin_amdgcn_s_setprio(1);
    #pragma unroll
    for (int f = 0; f < 8; ++f) {
      f32x4 z = {0.f,0.f,0.f,0.f}; s[f] = z;
      #pragma unroll
      for (int ks = 0; ks < 2; ++ks) {
        const int key = f * 16 + ql;
        bf16x8 a = *(const bf16x8*)((const char*)Ks + key * 128 +
                                    (((ks * 4 + g) ^ (key & 7)) << 4));
        s[f] = __builtin_amdgcn_mfma_f32_16x16x32_bf16(a, qf[ks], s[f], 0, 0, 0);
      }
    }
    __builtin_amdgcn_s_setprio(0);
    // s = log2-domain scores. Tile max:
    float rm = -1e30f;
    #pragma unroll
    for (int f = 0; f < 8; ++f)
      #pragma unroll
      for (int j = 0; j < 4; ++j) rm = fmaxf(rm, s[f][j]);
    rm = fmaxf(rm, __shfl_xor(rm, 16));
    rm = fmaxf(rm, __shfl_xor(rm, 32));
    // defer-max: rescale only when needed (wave-uniform decision)
    if (!__all(rm <= mmax + 11.5416f)) {
      const float nm = fmaxf(mmax, rm);
      const float sc = exp2_fast(mmax - nm);
      lsum *= sc;
      #pragma unroll
      for (int yf = 0; yf < 4; ++yf) acc[yf] *= sc;
      mmax = nm;
    }
    float rs = 0.f;
    #pragma unroll
    for (int f = 0; f < 8; ++f) {
      unsigned short p4[4];
      #pragma unroll
      for (int j = 0; j < 4; ++j) {
        const float pvj = exp2_fast(s[f][j] - mmax);
        rs += pvj;
        p4[j] = f2bf(pvj);
      }
      unsigned long long pk = (unsigned long long)p4[0] |
          ((unsigned long long)p4[1] << 16) |
          ((unsigned long long)p4[2] << 32) |
          ((unsigned long long)p4[3] << 48);
      const int sl = (f * 4 + g) ^ ((ql & 7) << 1);
      *(unsigned long long*)(psw + ql * 256 + sl * 8) = pk;
    }
    rs += __shfl_xor(rs, 16);
    rs += __shfl_xor(rs, 32);
    lsum += rs;
    __builtin_amdgcn_s_setprio(1);
    #pragma unroll
    for (int ks2 = 0; ks2 < 4; ++ks2) {
      const int sl2 = (ks2 * 8 + g * 2) ^ ((ql & 7) << 1);
      bf16x8 pa = *(const bf16x8*)(psw + ql * 256 + sl2 * 8);
      #pragma unroll
      for (int yf = 0; yf < 4; ++yf) {
        const int y = yf * 16 + ql;
        bf16x8 bk = *(const bf16x8*)((const char*)KTs + y * 256 +
                                     (((ks2 * 4 + g) ^ (y & 7)) << 4));
        acc[yf] = __builtin_amdgcn_mfma_f32_16x16x32_bf16(pa, bk, acc[yf], 0, 0, 0);
      }
    }
    __builtin_amdgcn_s_setprio(0);
    __syncthreads();
  }

  float linv[4];
  #pragma unroll
  for (int j = 0; j < 4; ++j)
    linv[j] = 1.0f / __shfl(lsum, (g << 4) + g * 4 + j);
  #pragma unroll
  for (int yf = 0; yf < 4; ++yf)
    #pragma unroll
    for (int j = 0; j < 4; ++j) {
      const int row = n0 + w * 16 + g * 4 + j;
      AqAk[((size_t)(b * N_ + row)) * LD + h * Y_ + yf * 16 + ql] =
          f2bf(acc[yf][j] * linv[j]);
    }
  if (g == 0)
    lse[((size_t)b * H_ + h) * N_ + n0 + w * 16 + ql] = mmax + log2_fast(lsum);
}

// ---------------------------------------------------------------------------
// Attention pass 2 (MFMA), KBLK=128 (8 waves), NBLK=128.
// S log2-domain; W = 2^(s - lse). Ak carries beta*log2e scale (qT scaled),
// compensated by 1/(beta*log2e) on B2's wkT panel.
// ---------------------------------------------------------------------------
__global__ __launch_bounds__(512) void attn2_mfma(
    const unsigned short* __restrict__ qk, const unsigned short* __restrict__ qT,
    const float* __restrict__ lse, unsigned short* __restrict__ AqAk) {
  __shared__ __align__(16) unsigned short Qs[128 * 64];
  __shared__ __align__(16) unsigned short QTs[64 * 128];
  __shared__ __align__(16) unsigned short Ws[8 * 16 * 128];
  __shared__ float lse_s[128];
  const int m0 = blockIdx.x * 128;
  const int h = blockIdx.y;
  const int b = blockIdx.z;
  const int t = threadIdx.x;
  const int w = t >> 6;            // 0..7
  const int l = t & 63;
  const int g = l >> 4;
  const int ql = l & 15;
  char* wsw = (char*)(Ws + w * 2048);
  const int LD = 1536;

  bf16x8 ka[2];
  {
    const unsigned short* krow =
        qk + ((size_t)(b * N_ + m0 + w * 16 + ql)) * LD + 768 + h * Y_;
    ka[0] = *(const bf16x8*)(krow + g * 8);
    ka[1] = *(const bf16x8*)(krow + 32 + g * 8);
  }
  const unsigned short* qbase = qk + (size_t)b * N_ * LD + h * Y_;
  const unsigned short* qTbase = qT + ((size_t)(b * H_ + h)) * Y_ * N_;
  const float* lbase = lse + ((size_t)b * H_ + h) * N_;

  f32x4 acc[4];
  #pragma unroll
  for (int yf = 0; yf < 4; ++yf) { f32x4 z = {0.f,0.f,0.f,0.f}; acc[yf] = z; }

  for (int nc = 0; nc < N_; nc += 128) {
    #pragma unroll
    for (int i = 0; i < 2; ++i) {
      const int flat = i * 8192 + t * 16;
      const int row = flat >> 7;
      const int slog = ((flat >> 4) & 7) ^ (row & 7);
      async_copy16(qbase + (size_t)(nc + row) * LD + slog * 8, (char*)Qs + flat);
    }
    #pragma unroll
    for (int i = 0; i < 2; ++i) {
      const int flat = i * 8192 + t * 16;
      const int row = flat >> 8;
      const int slog = ((flat >> 4) & 15) ^ (row & 7);
      async_copy16(qTbase + (size_t)row * N_ + nc + slog * 8, (char*)QTs + flat);
    }
    if (t < 128) lse_s[t] = lbase[nc + t];
    __syncthreads();

    f32x4 s[8];
    __builtin_amdgcn_s_setprio(1);
    #pragma unroll
    for (int f = 0; f < 8; ++f) {
      f32x4 z = {0.f,0.f,0.f,0.f}; s[f] = z;
      #pragma unroll
      for (int ks = 0; ks < 2; ++ks) {
        const int qr = f * 16 + ql;
        bf16x8 a = *(const bf16x8*)((const char*)Qs + qr * 128 +
                                    (((ks * 4 + g) ^ (qr & 7)) << 4));
        s[f] = __builtin_amdgcn_mfma_f32_16x16x32_bf16(a, ka[ks], s[f], 0, 0, 0);
      }
    }
    __builtin_amdgcn_s_setprio(0);
    #pragma unroll
    for (int f = 0; f < 8; ++f) {
      unsigned short w4[4];
      #pragma unroll
      for (int j = 0; j < 4; ++j) {
        const float wv = exp2_fast(s[f][j] - lse_s[f * 16 + g * 4 + j]);
        w4[j] = f2bf(wv);
      }
      unsigned long long pk =
          (unsigned long long)w4[0] | ((unsigned long long)w4[1] << 16) |
          ((unsigned long long)w4[2] << 32) | ((unsigned long long)w4[3] << 48);
      const int sl = (f * 4 + g) ^ ((ql & 7) << 1);
      *(unsigned long long*)(wsw + ql * 256 + sl * 8) = pk;
    }
    __builtin_amdgcn_s_setprio(1);
    #pragma unroll
    for (int ks2 = 0; ks2 < 4; ++ks2) {
      const int sl2 = (ks2 * 8 + g * 2) ^ ((ql & 7) << 1);
      bf16x8 wa = *(const bf16x8*)(wsw + ql * 256 + sl2 * 8);
      #pragma unroll
      for (int yf = 0; yf < 4; ++yf) {
        const int y = yf * 16 + ql;
        bf16x8 bq = *(const bf16x8*)((const char*)QTs + y * 256 +
                                     (((ks2 * 4 + g) ^ (y & 7)) << 4));
        acc[yf] = __builtin_amdgcn_mfma_f32_16x16x32_bf16(wa, bq, acc[yf], 0, 0, 0);
      }
    }
    __builtin_amdgcn_s_setprio(0);
    __syncthreads();
  }

  #pragma unroll
  for (int yf = 0; yf < 4; ++yf)
    #pragma unroll
    for (int j = 0; j < 4; ++j) {
      const int row = m0 + w * 16 + g * 4 + j;
      AqAk[((size_t)(b * N_ + row)) * LD + 768 + h * Y_ + yf * 16 + ql] =
          f2bf(acc[yf][j]);
    }
}

// ---------------------------------------------------------------------------
extern "C" void kernel_launch(void* const* d_in, const int* in_sizes, int n_in,
                              void* d_out, int out_size, void* d_ws, size_t ws_size,
                              hipStream_t stream) {
  const float* x0    = (const float*)d_in[0];
  const float* gamma = (const float*)d_in[1];
  const float* beta  = (const float*)d_in[2];
  const float* wq    = (const float*)d_in[3];
  const float* wk    = (const float*)d_in[4];
  const float* xi    = (const float*)d_in[5];
  float* x = (float*)d_out;

  const size_t SZ = (size_t)B_ * N_ * D_;   // 6291456
  char* wsp = (char*)d_ws;
  size_t off = 0;
  auto alloc = [&](size_t bytes) -> void* {
    off = (off + 255) & ~(size_t)255;
    void* p = wsp + off;
    off += bytes;
    return p;
  };
  unsigned short* g_bf   = (unsigned short*)alloc(SZ * 2);
  unsigned short* qk_bf  = (unsigned short*)alloc(SZ * 2 * 2);        // [8192][1536]
  unsigned short* AqAk   = (unsigned short*)alloc(SZ * 2 * 2);        // [8192][1536]
  unsigned short* qT_bf  = (unsigned short*)alloc(SZ * 2);
  unsigned short* kT_bf  = (unsigned short*)alloc(SZ * 2);
  float*          lse    = (float*)alloc((size_t)B_ * H_ * N_ * 4);
  unsigned short* wqk_bf = (unsigned short*)alloc((size_t)2 * D_ * D_ * 2);   // [1536][768]
  unsigned short* xi_bf  = (unsigned short*)alloc((size_t)M_ * D_ * 2);       // [3072][768]
  unsigned short* B2_bf  = (unsigned short*)alloc((size_t)D_ * (2 * D_ + M_) * 2); // [768][4608]
  unsigned short* hid_bf = (unsigned short*)alloc((size_t)B_ * N_ * M_ * 2);  // [8192][3072]

  const int WQN = D_ * D_;
  const int XIN = M_ * D_;
  const float SQ = BETA_ * LOG2E_;           // folded into q
  // B1 for proj: [SQ*wq; wk] rows
  cvt_bf16<<<(WQN + 255) / 256, 256, 0, stream>>>(wq, wqk_bf, WQN, SQ);
  cvt_bf16<<<(WQN + 255) / 256, 256, 0, stream>>>(wk, wqk_bf + (size_t)D_ * D_, WQN, 1.0f);
  cvt_bf16<<<(XIN + 255) / 256, 256, 0, stream>>>(xi, xi_bf, XIN, 1.0f);
  // B2 = [wqT | wkT/SQ | xiT] along k, ld 4608 (1/SQ compensates Ak scale)
  const int LDB2 = 2 * D_ + M_;  // 4608
  transpose_cvt<<<dim3(D_ / 32, D_ / 32), 256, 0, stream>>>(wq, B2_bf, D_, D_, LDB2, 0, 1.0f);
  transpose_cvt<<<dim3(D_ / 32, D_ / 32), 256, 0, stream>>>(wk, B2_bf, D_, D_, LDB2, D_, 1.0f / SQ);
  transpose_cvt<<<dim3(D_ / 32, M_ / 32), 256, 0, stream>>>(xi, B2_bf, M_, D_, LDB2, 2 * D_, 1.0f);

  hipMemcpyAsync(x, x0, SZ * sizeof(float), hipMemcpyDeviceToDevice, stream);

  const int MN = B_ * N_;  // 8192
  for (int step = 0; step < STEPS_; ++step) {
    ln_kernel<<<MN, 192, 0, stream>>>(x, gamma, beta, g_bf);
    // qk = g @ [SQ*Wq;Wk]^T -> [8192][1536] bf16, with fused qT/kT scatter
    gemm128<false, true><<<(1536 / 128) * (MN / 128), 256, 0, stream>>>(
        g_bf, wqk_bf, qk_bf, 1536, D_, 1536 / 128, qT_bf, kT_bf);
    // hid = relu(g @ xi^T) -> [8192][3072] bf16
    gemm128<true, false><<<(M_ / 128) * (MN / 128), 256, 0, stream>>>(
        g_bf, xi_bf, hid_bf, M_, D_, M_ / 128, nullptr, nullptr);
    // attention gradient pieces -> AqAk  (8-wave blocks, QBLK=128)
    attn1_mfma<<<dim3(N_ / 128, H_, B_), 512, 0, stream>>>(qk_bf, kT_bf, AqAk, lse);
    attn2_mfma<<<dim3(N_ / 128, H_, B_), 512, 0, stream>>>(qk_bf, qT_bf, lse, AqAk);
    // x += alpha * [AqAk | hid] @ B2^T   (BK=64, split K-loop)
    gemm_update<<<12 * (MN / 128), 256, 0, stream>>>(
        AqAk, hid_bf, B2_bf, x, ALPHA_);
  }
}